// Round 25
// baseline (335.824 us; speedup 1.0000x reference)
//
#include <hip/hip_runtime.h>
#include <hip/hip_fp16.h>
#include <hip/hip_fp8.h>
#include <math.h>
#include <type_traits>

#define N_NODES 50000
#define E_EDGES 1600000
#define TAU     0.5f
#define BN_EPS  1e-5f
#define SBSH    9                        // 512 dst nodes per super-bucket
#define NSB     ((N_NODES + 511) >> 9)   // 98 super-buckets
#define NSUBL   8                        // staging sub-lists (spread cursor LINES)
#define SUBCAP  2560                     // entries per sub-list (mean 2048 + >10 sigma)
#define BINCAP  48                       // LDS bin capacity (mean 10.4, +11 sigma)
#define EPB     1024                     // edges per scatter block
#define SCGRID  ((E_EDGES + EPB - 1) / EPB)
#define BSTR    16                       // cursor stride in ints (64B/line)

typedef _Float16 f16x8 __attribute__((ext_vector_type(8)));
typedef float    f32x4 __attribute__((ext_vector_type(4)));
typedef float    f32x2 __attribute__((ext_vector_type(2)));

// packed dual-FMA on f32 pairs (v_pk_fma_f32, gfx90a+): d = a*b + c
__device__ __forceinline__ f32x2 pk_fma(f32x2 a, f32x2 b, f32x2 c) {
  f32x2 d;
  asm volatile("v_pk_fma_f32 %0, %1, %2, %3"
               : "=v"(d) : "v"(a), "v"(b), "v"(c));
  return d;
}

// ---------------------------------------------------------------------------
// 1) normalized FP8 features + per-node scale: xn8 = e4m3(x/sc), sc=||x||+eps
__global__ __launch_bounds__(256) void xn_norm(
    const float* __restrict__ x, unsigned char* __restrict__ xn8,
    float* __restrict__ norms, int n) {
  int wid  = (int)((blockIdx.x * blockDim.x + threadIdx.x) >> 6);
  int lane = threadIdx.x & 63;
  if (wid >= n) return;
  float2 v = ((const float2*)(x + (size_t)wid * 128))[lane];
  float s = v.x * v.x + v.y * v.y;
  #pragma unroll
  for (int off = 32; off; off >>= 1) s += __shfl_xor(s, off);
  float sc = sqrtf(s) + 1e-12f;
  float inv = 1.0f / sc;
  __hip_fp8_e4m3 q0(v.x * inv), q1(v.y * inv);
  uchar2 pk;
  pk.x = q0.__x; pk.y = q1.__x;
  ((uchar2*)(xn8 + (size_t)wid * 128))[lane] = pk;
  if (lane == 0) norms[wid] = sc;
}

// ---------------------------------------------------------------------------
// 2a) LDS-binned scatter (unchanged)
__global__ __launch_bounds__(256) void scatter_sb(
    const int* __restrict__ src, const int* __restrict__ dst,
    int* __restrict__ gc, unsigned* __restrict__ staging,
    int* __restrict__ ocnt, unsigned* __restrict__ ostage, int e) {
  __shared__ unsigned bins[NSB][BINCAP];
  __shared__ int bcount[NSB];
  const int tid  = threadIdx.x;
  const int wv   = tid >> 6;
  const int lane = tid & 63;
  const int sl   = blockIdx.x & (NSUBL - 1);
  for (int i = tid; i < NSB; i += 256) bcount[i] = 0;
  __syncthreads();

  int base = blockIdx.x * EPB;
  int bend = min(base + EPB, e);
  for (int i = base + tid; i < bend; i += 256) {
    int d = dst[i], s = src[i];
    int sb = d >> SBSH;
    int pos = atomicAdd(&bcount[sb], 1);
    if (pos < BINCAP) {
      bins[sb][pos] = (unsigned)s | ((unsigned)(d & 511) << 16);
    } else {
      int op = atomicAdd(ocnt, 1);
      ostage[op] = (unsigned)s | ((unsigned)d << 16);   // full dst
    }
  }
  __syncthreads();

  for (int sb = wv; sb < NSB; sb += 4) {
    int cnt = min(bcount[sb], BINCAP);
    if (cnt > 0) {
      int cell = sb * NSUBL + sl;
      int gbase = 0;
      if (lane == 0) gbase = atomicAdd(&gc[cell * BSTR], cnt);
      gbase = __shfl(gbase, 0);
      if (gbase + cnt <= SUBCAP) {
        if (lane < cnt)
          staging[(size_t)cell * SUBCAP + gbase + lane] = bins[sb][lane];
      } else if (lane < cnt) {
        unsigned u = bins[sb][lane];
        int op = atomicAdd(ocnt, 1);
        ostage[op] = (u & 0xFFFFu) | ((unsigned)((sb << SBSH) | (u >> 16)) << 16);
      }
    }
  }
}

// ---------------------------------------------------------------------------
// 2b) per-SB LDS histogram -> deg + SB total
__global__ __launch_bounds__(256) void hist_sb(
    const unsigned* __restrict__ staging, const int* __restrict__ gc,
    int* __restrict__ deg, int* __restrict__ sbsum, int n) {
  __shared__ int h[512];
  __shared__ int wt[4];
  int sb = blockIdx.x;
  for (int i = threadIdx.x; i < 512; i += 256) h[i] = 0;
  __syncthreads();
  for (int s = 0; s < NSUBL; ++s) {
    int cell = sb * NSUBL + s;
    int m = min(gc[cell * BSTR], SUBCAP);
    for (int i = threadIdx.x; i < m; i += 256)
      atomicAdd(&h[(staging[(size_t)cell * SUBCAP + i] >> 16) & 511], 1);
  }
  __syncthreads();
  int d0 = sb << SBSH;
  for (int i = threadIdx.x; i < 512; i += 256)
    if (d0 + i < n) deg[d0 + i] = h[i];
  int t = h[threadIdx.x] + h[threadIdx.x + 256];
  #pragma unroll
  for (int off = 32; off; off >>= 1) t += __shfl_xor(t, off);
  if ((threadIdx.x & 63) == 0) wt[threadIdx.x >> 6] = t;
  __syncthreads();
  if (threadIdx.x == 0) sbsum[sb] = wt[0] + wt[1] + wt[2] + wt[3];
}

// ---------------------------------------------------------------------------
// 2b') overflow patch (no-op when ocnt==0)
__global__ __launch_bounds__(256) void overflow_deg(
    const unsigned* __restrict__ ostage, const int* __restrict__ ocnt,
    int* __restrict__ deg, int* __restrict__ sbsum) {
  int m = *ocnt;
  for (int i = blockIdx.x * blockDim.x + threadIdx.x; i < m;
       i += gridDim.x * blockDim.x) {
    int d = (int)(ostage[i] >> 16);
    atomicAdd(&deg[d], 1);
    atomicAdd(&sbsum[d >> SBSH], 1);
  }
}

// ---------------------------------------------------------------------------
// 3a) exclusive scan over the 98 SB sums
__global__ void scan_sb(const int* __restrict__ sbsum, int* __restrict__ sbbase,
                        int* __restrict__ rowptr, int n) {
  __shared__ int part[128];
  int t = (int)threadIdx.x;
  int v = (t < NSB) ? sbsum[t] : 0;
  part[t] = v;
  __syncthreads();
  for (int off = 1; off < 128; off <<= 1) {
    int u = (t >= off) ? part[t - off] : 0;
    __syncthreads();
    part[t] += u;
    __syncthreads();
  }
  if (t < NSB) sbbase[t] = part[t] - v;
  if (t == 127) rowptr[n] = part[127];
}

// ---------------------------------------------------------------------------
// 3b) rowptr within SB
__global__ __launch_bounds__(256) void rowptr_sb(
    const int* __restrict__ deg, const int* __restrict__ sbbase,
    int* __restrict__ rowptr, int n) {
  __shared__ int part[256];
  int sb = blockIdx.x;
  int d0 = sb << SBSH;
  int t = (int)threadIdx.x;
  int e0 = d0 + 2 * t;
  int v0 = (e0 < n) ? deg[e0] : 0;
  int v1 = (e0 + 1 < n) ? deg[e0 + 1] : 0;
  int s = v0 + v1;
  part[t] = s;
  __syncthreads();
  for (int off = 1; off < 256; off <<= 1) {
    int u = (t >= off) ? part[t - off] : 0;
    __syncthreads();
    part[t] += u;
    __syncthreads();
  }
  int ex = part[t] - s + sbbase[sb];
  if (e0 < n) rowptr[e0] = ex;
  if (e0 + 1 < n) rowptr[e0 + 1] = ex + v0;
}

// ---------------------------------------------------------------------------
// 2c) placement (unchanged)
__global__ __launch_bounds__(256) void place_sb(
    const unsigned* __restrict__ staging, const int* __restrict__ gc,
    const int* __restrict__ rowptr, unsigned short* __restrict__ csr16,
    int* __restrict__ gcur, int n) {
  __shared__ int cur[512];
  int sb = blockIdx.x;
  int d0 = sb << SBSH;
  for (int i = threadIdx.x; i < 512; i += 256)
    cur[i] = (d0 + i < n) ? rowptr[d0 + i] : 0;
  __syncthreads();
  for (int s = 0; s < NSUBL; ++s) {
    int cell = sb * NSUBL + s;
    int m = min(gc[cell * BSTR], SUBCAP);
    for (int i = threadIdx.x; i < m; i += 256) {
      unsigned u = staging[(size_t)cell * SUBCAP + i];
      int j = (u >> 16) & 511;
      int pos = atomicAdd(&cur[j], 1);
      csr16[pos] = (unsigned short)(u & 0xFFFFu);
    }
  }
  __syncthreads();
  for (int i = threadIdx.x; i < 512; i += 256)
    if (d0 + i < n) gcur[d0 + i] = cur[i];
}

// ---------------------------------------------------------------------------
// 2c') overflow placement (no-op when ocnt==0)
__global__ __launch_bounds__(256) void overflow_place(
    const unsigned* __restrict__ ostage, const int* __restrict__ ocnt,
    int* __restrict__ gcur, unsigned short* __restrict__ csr16) {
  int m = *ocnt;
  for (int i = blockIdx.x * blockDim.x + threadIdx.x; i < m;
       i += gridDim.x * blockDim.x) {
    unsigned u = ostage[i];
    int d = (int)(u >> 16);
    int pos = atomicAdd(&gcur[d], 1);
    csr16[pos] = (unsigned short)(u & 0xFFFFu);
  }
}

// ---------------------------------------------------------------------------
// 4) FUSED edge-weights + layer-0 aggregation, convert-once: xsv converted
// to f32 ONCE per edge (8 cvt), reused for dot (8 pk_fma + hadd, replacing
// 16 scalar FMA) and accumulate (8 pk_fma). xdv hoisted out of the loop.
__global__ __launch_bounds__(256) void fused_ew_agg0(
    const unsigned char* __restrict__ xn8, const float* __restrict__ norms,
    const int* __restrict__ rowptr, const unsigned short* __restrict__ csr_src16,
    unsigned* __restrict__ csrp, float* __restrict__ denom,
    __half* __restrict__ aggX, int n) {
  int wid  = (int)((blockIdx.x * blockDim.x + threadIdx.x) >> 6);
  int lane = threadIdx.x & 63;
  if (wid >= n) return;
  int grp = lane >> 3;     // edge slot 0..7
  int sub = lane & 7;      // 16-byte slice 0..7
  int beg = rowptr[wid], end = rowptr[wid + 1];

  // hoist dst fragment to f32 pairs (loop-invariant)
  f32x2 xd2[8];
  {
    int4 xdv = ((const int4*)(xn8 + (size_t)wid * 128))[sub];
    unsigned wd[4] = {(unsigned)xdv.x, (unsigned)xdv.y,
                      (unsigned)xdv.z, (unsigned)xdv.w};
    #pragma unroll
    for (int wi = 0; wi < 4; ++wi) {
      xd2[wi * 2 + 0] = __builtin_amdgcn_cvt_pk_f32_fp8(wd[wi], false);
      xd2[wi * 2 + 1] = __builtin_amdgcn_cvt_pk_f32_fp8(wd[wi], true);
    }
  }
  float wsum = 0.0f;

  f32x2 a2[8];
  #pragma unroll
  for (int k = 0; k < 8; ++k) a2[k] = (f32x2){0.f, 0.f};

  for (int base = beg; base < end; base += 64) {
    int m = min(64, end - base);
    int sv = (lane < m) ? (int)csr_src16[base + lane] : 0;
    int iters = (m + 7) >> 3;
    #pragma unroll 2
    for (int q = 0; q < iters; ++q) {
      int ei = q * 8 + grp;
      int s = __shfl(sv, ei);
      int4 xsv = ((const int4*)(xn8 + (size_t)s * 128))[sub];   // ONE gather
      // convert src fragment ONCE
      f32x2 xs2[8];
      {
        unsigned ws4[4] = {(unsigned)xsv.x, (unsigned)xsv.y,
                           (unsigned)xsv.z, (unsigned)xsv.w};
        #pragma unroll
        for (int wi = 0; wi < 4; ++wi) {
          xs2[wi * 2 + 0] = __builtin_amdgcn_cvt_pk_f32_fp8(ws4[wi], false);
          xs2[wi * 2 + 1] = __builtin_amdgcn_cvt_pk_f32_fp8(ws4[wi], true);
        }
      }
      // dot via packed FMA
      f32x2 dacc = {0.f, 0.f};
      #pragma unroll
      for (int k = 0; k < 8; ++k) dacc = pk_fma(xs2[k], xd2[k], dacc);
      float dp = dacc[0] + dacc[1];
      dp += __shfl_xor(dp, 1);
      dp += __shfl_xor(dp, 2);
      dp += __shfl_xor(dp, 4);
      bool valid = ei < m;
      float w = valid ? __expf(dp * (1.0f / TAU)) : 0.0f;
      wsum += w;
      if (valid && sub == 0) {
        unsigned w16 = (unsigned)__half_as_ushort(__float2half_rn(w));
        csrp[base + ei] = (unsigned)s | (w16 << 16);
      }
      // accumulate sum(w * x[src]) reusing xs2 (x[src] = xn8[src]*norms[src])
      float ws = w * norms[s];
      f32x2 w2 = {ws, ws};
      #pragma unroll
      for (int k = 0; k < 8; ++k) a2[k] = pk_fma(w2, xs2[k], a2[k]);
    }
  }
  wsum += __shfl_xor(wsum, 8);
  wsum += __shfl_xor(wsum, 16);
  wsum += __shfl_xor(wsum, 32);
  if (lane == 0) denom[wid] = wsum;

  #pragma unroll
  for (int off = 8; off <= 32; off <<= 1) {
    #pragma unroll
    for (int k = 0; k < 8; ++k) {
      a2[k][0] += __shfl_xor(a2[k][0], off);
      a2[k][1] += __shfl_xor(a2[k][1], off);
    }
  }

  if (lane < 8) {
    int c = sub * 16;
    #pragma unroll
    for (int v = 0; v < 2; ++v) {
      __half2 p0 = __floats2half2_rn(a2[v * 4 + 0][0], a2[v * 4 + 0][1]);
      __half2 p1 = __floats2half2_rn(a2[v * 4 + 1][0], a2[v * 4 + 1][1]);
      __half2 p2 = __floats2half2_rn(a2[v * 4 + 2][0], a2[v * 4 + 2][1]);
      __half2 p3 = __floats2half2_rn(a2[v * 4 + 3][0], a2[v * 4 + 3][1]);
      int4 pk4;
      pk4.x = *(int*)&p0; pk4.y = *(int*)&p1;
      pk4.z = *(int*)&p2; pk4.w = *(int*)&p3;
      ((int4*)(aggX + (size_t)wid * 128 + c))[v] = pk4;
    }
  }
}

// ---------------------------------------------------------------------------
// 4b) aggregation of fp8 H rows (layers 1/2): aggH = sum(w * H8[src]),
// fp16 output, unnormalized (gemm epilogue divides).
__global__ __launch_bounds__(256) void agg_h8(
    const unsigned char* __restrict__ H8, const int* __restrict__ rowptr,
    const unsigned* __restrict__ csrp, __half* __restrict__ aggH, int n) {
  int wid  = (int)((blockIdx.x * blockDim.x + threadIdx.x) >> 6);
  int lane = threadIdx.x & 63;
  if (wid >= n) return;
  int grp = lane >> 3;
  int sub = lane & 7;
  int beg = rowptr[wid], end = rowptr[wid + 1];

  f32x2 a2[8];
  #pragma unroll
  for (int k = 0; k < 8; ++k) a2[k] = (f32x2){0.f, 0.f};

  for (int base = beg; base < end; base += 64) {
    int m = min(64, end - base);
    unsigned pk = (lane < m) ? csrp[base + lane] : 0u;
    int iters = (m + 7) >> 3;
    #pragma unroll 4
    for (int q = 0; q < iters; ++q) {
      unsigned u = __shfl(pk, q * 8 + grp);
      int   s = (int)(u & 0xFFFFu);
      float w = __half2float(__ushort_as_half((unsigned short)(u >> 16)));
      f32x2 w2 = {w, w};
      int4 raw = ((const int4*)(H8 + (size_t)s * 128))[sub];
      unsigned ww[4] = {(unsigned)raw.x, (unsigned)raw.y,
                        (unsigned)raw.z, (unsigned)raw.w};
      #pragma unroll
      for (int wi = 0; wi < 4; ++wi) {
        f32x2 lo = __builtin_amdgcn_cvt_pk_f32_fp8(ww[wi], false);
        f32x2 hi = __builtin_amdgcn_cvt_pk_f32_fp8(ww[wi], true);
        a2[wi * 2 + 0] = pk_fma(w2, lo, a2[wi * 2 + 0]);
        a2[wi * 2 + 1] = pk_fma(w2, hi, a2[wi * 2 + 1]);
      }
    }
  }
  #pragma unroll
  for (int off = 8; off <= 32; off <<= 1) {
    #pragma unroll
    for (int k = 0; k < 8; ++k) {
      a2[k][0] += __shfl_xor(a2[k][0], off);
      a2[k][1] += __shfl_xor(a2[k][1], off);
    }
  }

  if (lane < 8) {
    int c = sub * 16;
    #pragma unroll
    for (int v = 0; v < 2; ++v) {
      __half2 p0 = __floats2half2_rn(a2[v * 4 + 0][0], a2[v * 4 + 0][1]);
      __half2 p1 = __floats2half2_rn(a2[v * 4 + 1][0], a2[v * 4 + 1][1]);
      __half2 p2 = __floats2half2_rn(a2[v * 4 + 2][0], a2[v * 4 + 2][1]);
      __half2 p3 = __floats2half2_rn(a2[v * 4 + 3][0], a2[v * 4 + 3][1]);
      int4 pk4;
      pk4.x = *(int*)&p0; pk4.y = *(int*)&p1;
      pk4.z = *(int*)&p2; pk4.w = *(int*)&p3;
      ((int4*)(aggH + (size_t)wid * 128 + c))[v] = pk4;
    }
  }
}

// ---------------------------------------------------------------------------
// 5a) weight prepack in MFMA fragment order (unchanged)
__global__ __launch_bounds__(256) void prep_weights(
    const float* __restrict__ Wn0, const float* __restrict__ Wr0,
    const float* __restrict__ Wn1, const float* __restrict__ Wr1,
    const float* __restrict__ Wn2, const float* __restrict__ Wr2,
    const float* __restrict__ cn0, const float* __restrict__ cr0,
    const float* __restrict__ cn1, const float* __restrict__ cr1,
    const float* __restrict__ cn2, const float* __restrict__ cr2,
    __half* __restrict__ WtN0, __half* __restrict__ WtR0,
    __half* __restrict__ WtN1, __half* __restrict__ WtR1,
    __half* __restrict__ WtN2, __half* __restrict__ WtR2,
    float* __restrict__ bias0, float* __restrict__ bias1,
    float* __restrict__ bias2) {
  int i = blockIdx.x * blockDim.x + threadIdx.x;
  const float* Ws[6] = {Wn0, Wr0, Wn1, Wr1, Wn2, Wr2};
  __half*     Wts[6] = {WtN0, WtR0, WtN1, WtR1, WtN2, WtR2};
  int seg = -1, off = 0;
  if (i < 65536)        { seg = i >> 14;               off = i & 16383; }
  else if (i < 81920)   { int j = i - 65536; seg = 4 + (j >> 13); off = j & 8191; }
  if (seg >= 0) {
    int DO = (seg < 4) ? 128 : 64;
    int c = off >> 7, k = off & 127;
    int t = c >> 4, kc = k >> 5, kgrp = (k >> 3) & 3, j = k & 7;
    int lane = (c & 15) | (kgrp << 4);
    int idx = (((t * 4 + kc) * 64 + lane) << 3) + j;
    Wts[seg][idx] = __float2half_rn(Ws[seg][(size_t)k * DO + c]);
  }
  if (i < 128) { bias0[i] = cn0[i] + cr0[i]; bias1[i] = cn1[i] + cr1[i]; }
  if (i < 64)  { bias2[i] = cn2[i] + cr2[i]; }
}

// ---------------------------------------------------------------------------
// 5b) post-agg dual MFMA GEMM: out = Agg@WfN * inv_denom + H@WfR + bias
// (+BN+ReLU for hidden layers). Hidden: writes H fp16 + H8 fp8; final:
// writes f32 straight to d_out. Z never materialized.
template <int DO, typename TIN1, bool DO_BN>
__global__ __launch_bounds__(256) void gemm_post(
    const __half* __restrict__ Agg, const TIN1* __restrict__ H,
    const __half* __restrict__ WfN, const __half* __restrict__ WfR,
    const float* __restrict__ bias, const float* __restrict__ denom,
    const float* __restrict__ g, const float* __restrict__ bb,
    const float* __restrict__ mm, const float* __restrict__ vv,
    void* __restrict__ outH, unsigned char* __restrict__ outH8, int n) {
  constexpr int NT = DO / 16;
  const int lane  = threadIdx.x & 63;
  const int w     = threadIdx.x >> 6;
  const int row0  = blockIdx.x * 64 + w * 16;
  const int col16 = lane & 15;
  const int kgrp  = (lane >> 4) * 8;
  const size_t arow = (size_t)min(row0 + col16, n - 1);

  f32x4 acc[2][NT];
  #pragma unroll
  for (int m = 0; m < 2; ++m)
    #pragma unroll
    for (int t = 0; t < NT; ++t) acc[m][t] = (f32x4){0.f, 0.f, 0.f, 0.f};

  #pragma unroll
  for (int kc = 0; kc < 4; ++kc) {
    f16x8 a0 = *(const f16x8*)(Agg + arow * 128 + kc * 32 + kgrp);
    f16x8 a1;
    if constexpr (std::is_same<TIN1, float>::value) {
      const float* hp = H + arow * 128 + kc * 32 + kgrp;
      float4 f0 = *(const float4*)hp;
      float4 f1 = *(const float4*)(hp + 4);
      a1[0] = (_Float16)f0.x; a1[1] = (_Float16)f0.y;
      a1[2] = (_Float16)f0.z; a1[3] = (_Float16)f0.w;
      a1[4] = (_Float16)f1.x; a1[5] = (_Float16)f1.y;
      a1[6] = (_Float16)f1.z; a1[7] = (_Float16)f1.w;
    } else {
      a1 = *(const f16x8*)(H + arow * 128 + kc * 32 + kgrp);
    }
    const f16x8* bN = (const f16x8*)(WfN + ((size_t)(kc * 64 + lane) << 3));
    const f16x8* bR = (const f16x8*)(WfR + ((size_t)(kc * 64 + lane) << 3));
    #pragma unroll
    for (int t = 0; t < NT; ++t) {
      f16x8 b = bN[t * 256];
      acc[0][t] = __builtin_amdgcn_mfma_f32_16x16x32_f16(a0, b, acc[0][t], 0, 0, 0);
    }
    #pragma unroll
    for (int t = 0; t < NT; ++t) {
      f16x8 b = bR[t * 256];
      acc[1][t] = __builtin_amdgcn_mfma_f32_16x16x32_f16(a1, b, acc[1][t], 0, 0, 0);
    }
  }

  const int rbase = (lane >> 4) * 4;
  float invd[4];
  #pragma unroll
  for (int j = 0; j < 4; ++j) {
    int row = row0 + rbase + j;
    invd[j] = 1.0f / (denom[min(row, n - 1)] + 1e-16f);
  }

  #pragma unroll
  for (int t = 0; t < NT; ++t) {
    int col = t * 16 + col16;
    float bz = bias[col];
    float sc = 0.f, sm = 0.f, sb2 = 0.f;
    if constexpr (DO_BN) {
      sc = g[col] * rsqrtf(vv[col] + BN_EPS);
      sm = mm[col];
      sb2 = bb[col];
    }
    #pragma unroll
    for (int j = 0; j < 4; ++j) {
      int row = row0 + rbase + j;
      if (row < n) {
        float o = fmaf(acc[0][t][j], invd[j], acc[1][t][j] + bz);
        if constexpr (DO_BN) {
          o = fmaxf(fmaf(o - sm, sc, sb2), 0.0f);
          ((__half*)outH)[(size_t)row * DO + col] = __float2half_rn(o);
          __hip_fp8_e4m3 q(o);
          outH8[(size_t)row * DO + col] = q.__x;
        } else {
          ((float*)outH)[(size_t)row * DO + col] = o;
        }
      }
    }
  }
}

// ---------------------------------------------------------------------------
extern "C" void kernel_launch(void* const* d_in, const int* in_sizes, int n_in,
                              void* d_out, int out_size, void* d_ws, size_t ws_size,
                              hipStream_t stream) {
  const float* x   = (const float*)d_in[0];
  const int*   ei  = (const int*)d_in[1];
  const float* Wn0 = (const float*)d_in[2];
  const float* cn0 = (const float*)d_in[3];
  const float* Wr0 = (const float*)d_in[4];
  const float* cr0 = (const float*)d_in[5];
  const float* Wn1 = (const float*)d_in[6];
  const float* cn1 = (const float*)d_in[7];
  const float* Wr1 = (const float*)d_in[8];
  const float* cr1 = (const float*)d_in[9];
  const float* Wn2 = (const float*)d_in[10];
  const float* cn2 = (const float*)d_in[11];
  const float* Wr2 = (const float*)d_in[12];
  const float* cr2 = (const float*)d_in[13];
  const float* g0  = (const float*)d_in[14];
  const float* b0  = (const float*)d_in[15];
  const float* m0  = (const float*)d_in[16];
  const float* v0  = (const float*)d_in[17];
  const float* g1  = (const float*)d_in[18];
  const float* b1  = (const float*)d_in[19];
  const float* m1  = (const float*)d_in[20];
  const float* v1  = (const float*)d_in[21];

  const int* src = ei;
  const int* dst = ei + E_EDGES;

  char* p = (char*)d_ws;
  auto alloc = [&](size_t bytes) {
    char* r = p;
    p += (bytes + 255) & ~(size_t)255;
    return r;
  };
  __half*         P0      = (__half*)        alloc((size_t)N_NODES * 128 * 2);  // xn8 -> H2
  __half*         P1      = (__half*)        alloc((size_t)N_NODES * 128 * 2);  // aggX/aggH
  __half*         A16     = (__half*)        alloc((size_t)N_NODES * 128 * 2);  // H1
  unsigned*       staging = (unsigned*)      alloc((size_t)NSB * NSUBL * SUBCAP * 4); // 8 MB -> H8
  int*            deg     = (int*)           alloc((size_t)N_NODES * 4);
  float*          denom   = (float*)         alloc((size_t)N_NODES * 4);
  float*          norms   = (float*)         alloc((size_t)N_NODES * 4);
  int*            rowptr  = (int*)           alloc((size_t)(N_NODES + 1) * 4);
  int*            gcur    = (int*)           alloc((size_t)N_NODES * 4);
  int*            sbsum   = (int*)           alloc((size_t)NSB * 4);
  int*            sbbase  = (int*)           alloc((size_t)NSB * 4);
  int*            gc      = (int*)           alloc((size_t)(NSB * NSUBL * BSTR + 16) * 4);
  unsigned short* csrs16  = (unsigned short*)alloc((size_t)E_EDGES * 2);
  unsigned*       csrp    = (unsigned*)      alloc((size_t)E_EDGES * 4);
  __half*         WtN0    = (__half*)        alloc(128 * 128 * 2);
  __half*         WtR0    = (__half*)        alloc(128 * 128 * 2);
  __half*         WtN1    = (__half*)        alloc(128 * 128 * 2);
  __half*         WtR1    = (__half*)        alloc(128 * 128 * 2);
  __half*         WtN2    = (__half*)        alloc(64 * 128 * 2);
  __half*         WtR2    = (__half*)        alloc(64 * 128 * 2);
  float*          bias0   = (float*)         alloc(128 * 4);
  float*          bias1   = (float*)         alloc(128 * 4);
  float*          bias2   = (float*)         alloc(64 * 4);

  // lifetimes: xn8 in P0 (dead after fused) -> H2 fp16 reuses P0.
  // H8 (fp8 6.4 MB, written by gemm0/gemm1) lives in staging (dead after place).
  unsigned char* xn8 = (unsigned char*)P0;
  unsigned char* H8  = (unsigned char*)staging;
  __half*        H2  = P0;

  // overflow list aliases csrp (csrp only written later by fused)
  unsigned* ostage = (unsigned*)csrp;
  int*      ocnt   = gc + NSB * NSUBL * BSTR;   // covered by gc memset

  hipMemsetAsync(gc, 0, (size_t)(NSB * NSUBL * BSTR + 16) * 4, stream);

  const int node_grid = (N_NODES * 64 + 255) / 256;
  const int gemm_grid = (N_NODES + 63) / 64;

  xn_norm<<<node_grid, 256, 0, stream>>>(x, xn8, norms, N_NODES);
  prep_weights<<<320, 256, 0, stream>>>(Wn0, Wr0, Wn1, Wr1, Wn2, Wr2,
                                        cn0, cr0, cn1, cr1, cn2, cr2,
                                        WtN0, WtR0, WtN1, WtR1, WtN2, WtR2,
                                        bias0, bias1, bias2);
  scatter_sb<<<SCGRID, 256, 0, stream>>>(src, dst, gc, staging, ocnt, ostage, E_EDGES);
  hist_sb<<<NSB, 256, 0, stream>>>(staging, gc, deg, sbsum, N_NODES);
  overflow_deg<<<64, 256, 0, stream>>>(ostage, ocnt, deg, sbsum);
  scan_sb<<<1, 128, 0, stream>>>(sbsum, sbbase, rowptr, N_NODES);
  rowptr_sb<<<NSB, 256, 0, stream>>>(deg, sbbase, rowptr, N_NODES);
  place_sb<<<NSB, 256, 0, stream>>>(staging, gc, rowptr, csrs16, gcur, N_NODES);
  overflow_place<<<64, 256, 0, stream>>>(ostage, ocnt, gcur, csrs16);

  // layer 0: fused edge-weight + raw-x aggregation (single gather), then gemm
  fused_ew_agg0<<<node_grid, 256, 0, stream>>>(
      xn8, norms, rowptr, csrs16, csrp, denom, P1, N_NODES);
  gemm_post<128, float, true><<<gemm_grid, 256, 0, stream>>>(
      P1, x, WtN0, WtR0, bias0, denom, g0, b0, m0, v0, A16, H8, N_NODES);

  // layer 1: agg over H1 fp8, then gemm -> H2 (P0; xn8 dead) + H8
  agg_h8<<<node_grid, 256, 0, stream>>>(H8, rowptr, csrp, P1, N_NODES);
  gemm_post<128, __half, true><<<gemm_grid, 256, 0, stream>>>(
      P1, A16, WtN1, WtR1, bias1, denom, g1, b1, m1, v1, H2, H8, N_NODES);

  // layer 2: agg over H2 fp8, then gemm straight to d_out (f32)
  agg_h8<<<node_grid, 256, 0, stream>>>(H8, rowptr, csrp, P1, N_NODES);
  gemm_post<64, __half, false><<<gemm_grid, 256, 0, stream>>>(
      P1, H2, WtN2, WtR2, bias2, denom,
      nullptr, nullptr, nullptr, nullptr, d_out, nullptr, N_NODES);
}